// Round 2
// baseline (147.217 us; speedup 1.0000x reference)
//
#include <hip/hip_runtime.h>
#include <cstddef>

#define B     4
#define DEC   256
#define ENC   1024
#define HID   512
#define UNITS 128

// proj outputs are EXPONENTIATED: Z = 2^(2*log2e * proj) so the score kernel
// computes tanh via  tanh(q+k) = 1 - 2/(1 + Zq*Zk)  with NO exp in the
// 134M-eval inner loop (exp moved to the 655K-eval proj epilogue).
#define PROJ_SCALE 2.8853900817779268f   // 2 * log2(e)

// ---------------------------------------------------------------------------
// v_pk_fma_f32 helpers (VOP3P packed 2xfp32, IEEE-exact — no numerics change).
// _blo/_bhi broadcast the lo/hi half of src0 to BOTH result lanes via op_sel,
// so a scalar weight multiplies a float2 without any v_mov duplication.
//   default:        d.lo = a.lo*b.lo+c.lo ; d.hi = a.hi*b.hi+c.hi
//   blo (op_sel_hi[0]=0): d.lo = a.lo*b.lo+c.lo ; d.hi = a.lo*b.hi+c.hi
//   bhi (op_sel[0]=1):    d.lo = a.hi*b.lo+c.lo ; d.hi = a.hi*b.hi+c.hi
// ---------------------------------------------------------------------------
__device__ __forceinline__ float2 pk_fma(float2 a, float2 b, float2 c) {
    float2 d;
    asm("v_pk_fma_f32 %0, %1, %2, %3" : "=v"(d) : "v"(a), "v"(b), "v"(c));
    return d;
}
__device__ __forceinline__ float2 pk_fma_blo(float2 a, float2 b, float2 c) {
    float2 d;
    asm("v_pk_fma_f32 %0, %1, %2, %3 op_sel:[0,0,0] op_sel_hi:[0,1,1]"
        : "=v"(d) : "v"(a), "v"(b), "v"(c));
    return d;
}
__device__ __forceinline__ float2 pk_fma_bhi(float2 a, float2 b, float2 c) {
    float2 d;
    asm("v_pk_fma_f32 %0, %1, %2, %3 op_sel:[1,0,0] op_sel_hi:[1,1,1]"
        : "=v"(d) : "v"(a), "v"(b), "v"(c));
    return d;
}

// ---------------------------------------------------------------------------
// Kernel 1: projections. Block = 8 rows x 128 units; each wave handles a
// 128-wide h-quarter (all 8 rows), partials reduced across waves via LDS.
// X reads are wave-uniform; W reads lane-coalesced float2 (lane owns units
// 2l, 2l+1), depth-1 software prefetch. Inner loop is v_pk_fma_f32: 32
// packed fma/iter (was 64 scalar). Epilogue applies 2^x. q rows -> qbuf
// row-major; k rows -> kbufT [b][c=u/4][e][u%4] for coalesced score loads.
// ---------------------------------------------------------------------------
__global__ __launch_bounds__(256) void proj_kernel(
    const float* __restrict__ query, const float* __restrict__ value,
    const float* __restrict__ W1,    const float* __restrict__ W2,
    float* __restrict__ qbuf,        float* __restrict__ kbufT)
{
    __shared__ float part[4][8][UNITS];   // 16 KB

    const int tid  = threadIdx.x;
    const int lane = tid & 63;
    const int wv   = __builtin_amdgcn_readfirstlane(tid >> 6);
    const int row0g = blockIdx.x * 8;
    const bool isQ = row0g < B * DEC;
    const float* X = isQ ? query : value;
    const float* W = isQ ? W1 : W2;
    const int row0 = isQ ? row0g : row0g - B * DEC;
    const int h0   = wv * 128;            // this wave's h-quarter

    float2 acc2[8];
    #pragma unroll
    for (int r = 0; r < 8; ++r) acc2[r] = make_float2(0.f, 0.f);

    const float* Xb = X + (size_t)row0 * HID + h0;
    const float* Wb = W + (size_t)h0 * UNITS;

    // preload W group 0: lane owns units (2*lane, 2*lane+1)
    float2 wv2[4];
    #pragma unroll
    for (int j = 0; j < 4; ++j)
        wv2[j] = *(const float2*)(Wb + j * UNITS + 2 * lane);

    for (int h = 0; h < 128; h += 4) {
        // prefetch next W group (clamped; last iteration reloads current)
        const int hp = (h + 4 < 128) ? h + 4 : h;
        float2 nv[4];
        #pragma unroll
        for (int j = 0; j < 4; ++j)
            nv[j] = *(const float2*)(Wb + (hp + j) * UNITS + 2 * lane);

        #pragma unroll
        for (int r = 0; r < 8; ++r) {
            const float4 xv = *(const float4*)(Xb + r * HID + h);  // wave-uniform
            const float2* xp = (const float2*)&xv;
            acc2[r] = pk_fma_blo(xp[0], wv2[0], acc2[r]);   // xv.x * w(h+0)
            acc2[r] = pk_fma_bhi(xp[0], wv2[1], acc2[r]);   // xv.y * w(h+1)
            acc2[r] = pk_fma_blo(xp[1], wv2[2], acc2[r]);   // xv.z * w(h+2)
            acc2[r] = pk_fma_bhi(xp[1], wv2[3], acc2[r]);   // xv.w * w(h+3)
        }
        #pragma unroll
        for (int j = 0; j < 4; ++j) wv2[j] = nv[j];
    }

    #pragma unroll
    for (int r = 0; r < 8; ++r)
        *(float2*)&part[wv][r][2 * lane] = acc2[r];
    __syncthreads();

    // cross-wave reduce + 2^x epilogue: 1024 outputs, 4 per thread
    #pragma unroll
    for (int k = 0; k < 4; ++k) {
        const int idx = tid + k * 256;
        const int r = idx >> 7, u = idx & (UNITS - 1);
        const float s = PROJ_SCALE *
            ((part[0][r][u] + part[1][r][u]) + (part[2][r][u] + part[3][r][u]));
        const float z = __builtin_amdgcn_exp2f(s);   // Z = 2^(2*log2e*proj)
        const int row = row0 + r;
        if (isQ) {
            qbuf[(size_t)row * UNITS + u] = z;
        } else {
            const int bb = row >> 10, e = row & (ENC - 1);
            const int c = u >> 2, j = u & 3;
            kbufT[((size_t)bb * 32 * ENC + (size_t)c * ENC + e) * 4 + j] = z;
        }
    }
}

// quad fused sigmoid-sum: s.x/A + s.y/B + s.z/C + s.w/D with ONE rcp,
// where A = 1+q.x*k.x etc. Exact algebra:
//   (s0*BCD + s1*ACD + s2*ABD + s3*ABC) / (ABCD)
// Denominator pairs via v_pk_fma_f32: 12 VALU + 1 trans per 4 units.
// Overflow: log(ABCD) ~ N(0, 5.7) for this data; fp32 overflow needs >88.
__device__ __forceinline__ float quad_term(const float4 q, const float4 k,
                                           const float4 s, const float2 one2) {
    const float2* qp = (const float2*)&q;
    const float2* kp = (const float2*)&k;
    const float2 P1 = pk_fma(qp[0], kp[0], one2);    // (A, B)
    const float2 P2 = pk_fma(qp[1], kp[1], one2);    // (C, D)
    const float AB = P1.x * P1.y, CD = P2.x * P2.y;
    const float n1 = fmaf(s.x, P1.y, s.y * P1.x);
    const float n2 = fmaf(s.z, P2.y, s.w * P2.x);
    const float num = fmaf(n1, CD, n2 * AB);
    return num * __builtin_amdgcn_rcpf(AB * CD);
}

// ---------------------------------------------------------------------------
// Kernel 2: scores + masked softmax. DQ=4 dec rows per block, 256 blocks x
// 1024 threads. Loop is VALU-bound; this version packs the 4 sigmoid
// denominators into 2 v_pk_fma_f32 (12 VALU + 1 trans per quad, was 14+1)
// and DROPS the S0 = sum(scale) pass entirely: S0 is constant across e and
// r, so it cancels exactly in softmax  exp(S0-2t)/sum == exp(-2t)/sum.
// Range safe: |2t| <= 2*sum|scale| ~ 18. Masked lanes contribute exactly 0.
// q/scale reads wave-uniform, kv coalesced b128, depth-1 prefetch.
// XCD-swizzled: b pinned to an XCD pair (kbufT[b] = 512 KB in L2).
// ---------------------------------------------------------------------------
__global__ __launch_bounds__(1024) void score_kernel(
    const float* __restrict__ qbuf, const float* __restrict__ kbufT,
    const int* __restrict__ mask,   const float* __restrict__ scale,
    float* __restrict__ attn_out)
{
    const int bi  = blockIdx.x;                      // 0..255
    const int b   = (bi >> 1) & 3;                   // XCD-pair pinning
    const int dq0 = (((bi >> 3) << 1) | (bi & 1)) * 4;
    const int tid = threadIdx.x;                     // 0..1023 == e

    const int m = mask[b * ENC + tid];               // early, independent load

    const float* q0 = qbuf + (size_t)(b * DEC + dq0) * UNITS;
    const float* kc = kbufT + (size_t)b * 32 * ENC * 4 + (size_t)tid * 4;

    const float2 one2 = make_float2(1.f, 1.f);
    float t0 = 0.f, t1 = 0.f, t2 = 0.f, t3 = 0.f;

    float4 kv = *(const float4*)kc;                  // depth-1 kv prefetch
    for (int i = 0; i < 32; ++i) {
        float4 nkv;
        if (i + 1 < 32) nkv = *(const float4*)(kc + (size_t)(i + 1) * ENC * 4);
        const float4 sv = *(const float4*)(scale + i * 4);              // uniform
        const float4 qa = *(const float4*)(q0 + 0 * UNITS + i * 4);     // uniform
        const float4 qb = *(const float4*)(q0 + 1 * UNITS + i * 4);
        const float4 qc = *(const float4*)(q0 + 2 * UNITS + i * 4);
        const float4 qd = *(const float4*)(q0 + 3 * UNITS + i * 4);

        t0 += quad_term(qa, kv, sv, one2);
        t1 += quad_term(qb, kv, sv, one2);
        t2 += quad_term(qc, kv, sv, one2);
        t3 += quad_term(qd, kv, sv, one2);

        if (i + 1 < 32) kv = nkv;
    }

    // unnormalized weights (S0 cancels in softmax); masked lanes exactly 0
    float wgt[4];
    wgt[0] = m ? __expf(-2.f * t0) : 0.f;
    wgt[1] = m ? __expf(-2.f * t1) : 0.f;
    wgt[2] = m ? __expf(-2.f * t2) : 0.f;
    wgt[3] = m ? __expf(-2.f * t3) : 0.f;

    __shared__ float reds[4][16];
    const int lane = tid & 63, wv = tid >> 6;   // 16 waves

    float ls[4] = {wgt[0], wgt[1], wgt[2], wgt[3]};
    #pragma unroll
    for (int off = 32; off > 0; off >>= 1) {
        #pragma unroll
        for (int r = 0; r < 4; ++r)
            ls[r] += __shfl_down(ls[r], off, 64);
    }
    if (lane == 0) {
        #pragma unroll
        for (int r = 0; r < 4; ++r) reds[r][wv] = ls[r];
    }
    __syncthreads();
    #pragma unroll
    for (int r = 0; r < 4; ++r) {
        float g = 0.f;
        #pragma unroll
        for (int w = 0; w < 16; ++w) g += reds[r][w];
        attn_out[(size_t)(b * DEC + dq0 + r) * ENC + tid] =
            wgt[r] * __builtin_amdgcn_rcpf(g);
    }
}

// ---------------------------------------------------------------------------
// Kernel 3: ctx = attn @ value. 512 blocks x 512 threads: 8 dec rows x 128
// h-cols per block. Attention rows staged in LDS via flat float4 copies;
// weights fetched as same-address ds_read_b128 broadcasts. Inner loop is
// v_pk_fma_f32 with op_sel scalar-weight broadcast: 32 packed fma/group
// (was 64 scalar) -> LDS b128 stream and packed-fma stream co-issue.
// Value loads software-pipelined depth-1. 8-way cross-wave reduce via LDS.
// ---------------------------------------------------------------------------
__global__ __launch_bounds__(512) void ctx_kernel(
    const float* __restrict__ attn, const float* __restrict__ value,
    float* __restrict__ ctx)
{
    __shared__ float attnS[8][ENC];     // 32 KB
    __shared__ float part[8][8][128];   // 32 KB

    const int bi   = blockIdx.x;                 // 0..511, XCD-swizzled
    const int b    = (bi >> 1) & 3;              // b pinned to an XCD pair
    const int idx  = ((bi >> 3) << 1) | (bi & 1);
    const int row0 = (idx >> 2) * 8;
    const int h0   = (idx & 3) * 128;
    const int tid  = threadIdx.x;
    const int lane = tid & 63;
    const int wv   = __builtin_amdgcn_readfirstlane(tid >> 6);  // 0..7

    // stage 8 attention rows: 8192 contiguous floats, 4x float4 per thread
    const float* ab = attn + (size_t)(b * DEC + row0) * ENC;
    #pragma unroll
    for (int k = 0; k < 4; ++k) {
        const float4 v = *(const float4*)(ab + (size_t)k * 2048 + tid * 4);
        *(float4*)&attnS[0][k * 2048 + tid * 4] = v;
    }
    __syncthreads();

    float2 acc2[8];
    #pragma unroll
    for (int r = 0; r < 8; ++r) acc2[r] = make_float2(0.f, 0.f);

    const float* vb = value + (size_t)b * ENC * HID + h0 + lane * 2;
    const int e0 = wv * 128;

    // preload group 0's value columns
    float2 va[4];
    #pragma unroll
    for (int j = 0; j < 4; ++j)
        va[j] = *(const float2*)(vb + (size_t)(e0 + j) * HID);

    for (int g = 0; g < 32; ++g) {                // 4-e groups
        const int gp = (g + 1 < 32) ? g + 1 : g;  // clamped prefetch
        float2 vn[4];
        #pragma unroll
        for (int j = 0; j < 4; ++j)
            vn[j] = *(const float2*)(vb + (size_t)(e0 + gp * 4 + j) * HID);

        const int eg = e0 + g * 4;
        float4 w4[8];
        #pragma unroll
        for (int r = 0; r < 8; ++r)
            w4[r] = *(const float4*)&attnS[r][eg];   // same-addr broadcast b128

        #pragma unroll
        for (int r = 0; r < 8; ++r) {
            const float2* wp = (const float2*)&w4[r];
            acc2[r] = pk_fma_blo(wp[0], va[0], acc2[r]);   // w(e+0) * v
            acc2[r] = pk_fma_bhi(wp[0], va[1], acc2[r]);   // w(e+1) * v
            acc2[r] = pk_fma_blo(wp[1], va[2], acc2[r]);   // w(e+2) * v
            acc2[r] = pk_fma_bhi(wp[1], va[3], acc2[r]);   // w(e+3) * v
        }
        #pragma unroll
        for (int j = 0; j < 4; ++j) va[j] = vn[j];
    }

    #pragma unroll
    for (int r = 0; r < 8; ++r)
        *(float2*)&part[wv][r][lane * 2] = acc2[r];
    __syncthreads();

    // 8-way cross-wave reduce: 1024 outputs, 2 per thread, stride-1 in h
    #pragma unroll
    for (int k = 0; k < 2; ++k) {
        const int idx2 = tid + k * 512;
        const int r = idx2 >> 7, hh = idx2 & 127;
        float s = 0.f;
        #pragma unroll
        for (int w = 0; w < 8; ++w) s += part[w][r][hh];
        ctx[(size_t)(b * DEC + row0 + r) * HID + h0 + hh] = s;
    }
}

extern "C" void kernel_launch(void* const* d_in, const int* in_sizes, int n_in,
                              void* d_out, int out_size, void* d_ws, size_t ws_size,
                              hipStream_t stream) {
    const float* query = (const float*)d_in[0];
    const float* value = (const float*)d_in[1];
    const int*   mask  = (const int*)  d_in[2];
    const float* W1    = (const float*)d_in[3];
    const float* W2    = (const float*)d_in[4];
    const float* scale = (const float*)d_in[5];

    float* qbuf  = (float*)d_ws;                       // B*DEC*UNITS   = 131072 floats
    float* kbufT = qbuf + (size_t)B * DEC * UNITS;     // B*32*ENC*4    = 524288 floats

    float* ctx_out  = (float*)d_out;                   // B*DEC*HID
    float* attn_out = ctx_out + (size_t)B * DEC * HID; // B*DEC*ENC

    proj_kernel <<<640,  256, 0, stream>>>(query, value, W1, W2, qbuf, kbufT);
    score_kernel<<<256, 1024, 0, stream>>>(qbuf, kbufT, mask, scale, attn_out);
    ctx_kernel  <<<512,  512, 0, stream>>>(attn_out, value, ctx_out);
}

// Round 3
// 121.721 us; speedup vs baseline: 1.2095x; 1.2095x over previous
//
#include <hip/hip_runtime.h>
#include <cstddef>

#define B     4
#define DEC   256
#define ENC   1024
#define HID   512
#define UNITS 128

// proj outputs are EXPONENTIATED: Z = 2^(2*log2e * proj) so the score kernel
// computes tanh via  tanh(q+k) = 1 - 2/(1 + Zq*Zk)  with NO exp in the
// 134M-eval inner loop (exp moved to the 655K-eval proj epilogue).
#define PROJ_SCALE 2.8853900817779268f   // 2 * log2(e)

// ---------------------------------------------------------------------------
// Kernel 1: projections. Block = 8 rows x 128 units; wave w handles h-quarter
// [128w, 128w+128), lane owns units (2l, 2l+1); cross-wave reduce via LDS.
//
// R2 post-mortem: the old version was LATENCY-SERIALIZED (42 us, VGPR=32,
// VALUBusy 12%, 280 GB/s): X and W loads issued load->use->use serially.
// Fix: X tile (8 rows x 512 = 16 KB, flat-contiguous) is staged in LDS with
// 4 concurrent coalesced float4 loads/thread; the inner loop reads X as
// broadcast ds_read_b128 (LDS pipe, no vmem latency) and only W streams from
// L2 with a DEPTH-2 register prefetch (~256 cyc slack >= L2 latency).
// Epilogue applies 2^x. q rows -> qbuf row-major; k rows -> kbufT
// [b][c=u/4][e][u%4] so score k-loads are coalesced b128.
// ---------------------------------------------------------------------------
__global__ __launch_bounds__(256) void proj_kernel(
    const float* __restrict__ query, const float* __restrict__ value,
    const float* __restrict__ W1,    const float* __restrict__ W2,
    float* __restrict__ qbuf,        float* __restrict__ kbufT)
{
    __shared__ float xs[8][HID];          // 16 KB X tile
    __shared__ float part[4][8][UNITS];   // 16 KB partials

    const int tid  = threadIdx.x;
    const int lane = tid & 63;
    const int wv   = __builtin_amdgcn_readfirstlane(tid >> 6);
    const int row0g = blockIdx.x * 8;
    const bool isQ = row0g < B * DEC;
    const float* X = isQ ? query : value;
    const float* W = isQ ? W1 : W2;
    const int row0 = isQ ? row0g : row0g - B * DEC;
    const int h0   = wv * 128;            // this wave's h-quarter

    // ---- stage X: 8 rows are contiguous (row stride == HID), flat copy of
    // 4096 floats; 4 independent float4 loads per thread, all in flight.
    {
        const float* xb = X + (size_t)row0 * HID;
        #pragma unroll
        for (int k = 0; k < 4; ++k) {
            const float4 v = *(const float4*)(xb + (size_t)k * 1024 + tid * 4);
            *(float4*)&xs[0][k * 1024 + tid * 4] = v;
        }
    }
    __syncthreads();

    float acc0[8], acc1[8];
    #pragma unroll
    for (int r = 0; r < 8; ++r) { acc0[r] = 0.f; acc1[r] = 0.f; }

    const float* Wb = W + (size_t)h0 * UNITS + 2 * lane;

    // ---- depth-2 W prefetch: groups h and h+4 live in registers.
    float2 wcur[4], wnxt[4];
    #pragma unroll
    for (int j = 0; j < 4; ++j) wcur[j] = *(const float2*)(Wb + j * UNITS);
    #pragma unroll
    for (int j = 0; j < 4; ++j) wnxt[j] = *(const float2*)(Wb + (4 + j) * UNITS);

    for (int h = 0; h < 128; h += 4) {
        // prefetch group h+8 (clamped; last two iters reload current)
        const int hp = (h + 8 < 128) ? h + 8 : h;
        float2 np[4];
        #pragma unroll
        for (int j = 0; j < 4; ++j)
            np[j] = *(const float2*)(Wb + (hp + j) * UNITS);

        #pragma unroll
        for (int r = 0; r < 8; ++r) {
            const float4 xv = *(const float4*)&xs[r][h0 + h];  // broadcast b128
            acc0[r] = fmaf(xv.x, wcur[0].x, acc0[r]);
            acc1[r] = fmaf(xv.x, wcur[0].y, acc1[r]);
            acc0[r] = fmaf(xv.y, wcur[1].x, acc0[r]);
            acc1[r] = fmaf(xv.y, wcur[1].y, acc1[r]);
            acc0[r] = fmaf(xv.z, wcur[2].x, acc0[r]);
            acc1[r] = fmaf(xv.z, wcur[2].y, acc1[r]);
            acc0[r] = fmaf(xv.w, wcur[3].x, acc0[r]);
            acc1[r] = fmaf(xv.w, wcur[3].y, acc1[r]);
        }
        #pragma unroll
        for (int j = 0; j < 4; ++j) { wcur[j] = wnxt[j]; wnxt[j] = np[j]; }
    }

    #pragma unroll
    for (int r = 0; r < 8; ++r)
        *(float2*)&part[wv][r][2 * lane] = make_float2(acc0[r], acc1[r]);
    __syncthreads();

    // cross-wave reduce + 2^x epilogue: 1024 outputs, 4 per thread
    #pragma unroll
    for (int k = 0; k < 4; ++k) {
        const int idx = tid + k * 256;
        const int r = idx >> 7, u = idx & (UNITS - 1);
        const float s = PROJ_SCALE *
            ((part[0][r][u] + part[1][r][u]) + (part[2][r][u] + part[3][r][u]));
        const float z = __builtin_amdgcn_exp2f(s);   // Z = 2^(2*log2e*proj)
        const int row = row0 + r;
        if (isQ) {
            qbuf[(size_t)row * UNITS + u] = z;
        } else {
            const int bb = row >> 10, e = row & (ENC - 1);
            const int c = u >> 2, j = u & 3;
            kbufT[((size_t)bb * 32 * ENC + (size_t)c * ENC + e) * 4 + j] = z;
        }
    }
}

// quad fused sigmoid-sum: s.x/A + s.y/B + s.z/C + s.w/D with ONE rcp,
// where A = 1+q.x*k.x etc. Exact algebra:
//   (s0*BCD + s1*ACD + s2*ABD + s3*ABC) / (ABCD)
// 14 VALU + 1 trans per 4 units. Overflow: log(ABCD) ~ N(0, 5.7) for this
// data; fp32 overflow needs >88.
__device__ __forceinline__ float quad_term(const float4 q, const float4 k,
                                           const float4 s) {
    const float A  = fmaf(q.x, k.x, 1.f);
    const float B_ = fmaf(q.y, k.y, 1.f);
    const float C  = fmaf(q.z, k.z, 1.f);
    const float D  = fmaf(q.w, k.w, 1.f);
    const float AB = A * B_, CD = C * D;
    const float n1 = fmaf(s.x, B_, s.y * A);
    const float n2 = fmaf(s.z, D,  s.w * C);
    const float num = fmaf(n1, CD, n2 * AB);
    return num * __builtin_amdgcn_rcpf(AB * CD);
}

// ---------------------------------------------------------------------------
// Kernel 2: scores + masked softmax. DQ=4 dec rows per block, 256 blocks x
// 1024 threads (R8 grid — best measured). Quad combining: 4 rcp/iter.
// S0 = sum(scale) DROPPED: constant across e and r, cancels exactly in
// softmax  exp(S0-2t)/sum == exp(-2t)/sum  (range safe: |2t| <= 18).
// Masked lanes contribute exactly 0. q/scale reads wave-uniform,
// kv coalesced b128, depth-1 prefetch. XCD-swizzled: b pinned to an XCD
// pair (kbufT[b] = 512 KB in L2).
// ---------------------------------------------------------------------------
__global__ __launch_bounds__(1024) void score_kernel(
    const float* __restrict__ qbuf, const float* __restrict__ kbufT,
    const int* __restrict__ mask,   const float* __restrict__ scale,
    float* __restrict__ attn_out)
{
    const int bi  = blockIdx.x;                      // 0..255
    const int b   = (bi >> 1) & 3;                   // XCD-pair pinning
    const int dq0 = (((bi >> 3) << 1) | (bi & 1)) * 4;
    const int tid = threadIdx.x;                     // 0..1023 == e

    const int m = mask[b * ENC + tid];               // early, independent load

    const float* q0 = qbuf + (size_t)(b * DEC + dq0) * UNITS;
    const float* kc = kbufT + (size_t)b * 32 * ENC * 4 + (size_t)tid * 4;

    float t0 = 0.f, t1 = 0.f, t2 = 0.f, t3 = 0.f;

    float4 kv = *(const float4*)kc;                  // depth-1 kv prefetch
    for (int i = 0; i < 32; ++i) {
        float4 nkv;
        if (i + 1 < 32) nkv = *(const float4*)(kc + (size_t)(i + 1) * ENC * 4);
        const float4 sv = *(const float4*)(scale + i * 4);              // uniform
        const float4 qa = *(const float4*)(q0 + 0 * UNITS + i * 4);     // uniform
        const float4 qb = *(const float4*)(q0 + 1 * UNITS + i * 4);
        const float4 qc = *(const float4*)(q0 + 2 * UNITS + i * 4);
        const float4 qd = *(const float4*)(q0 + 3 * UNITS + i * 4);

        t0 += quad_term(qa, kv, sv);
        t1 += quad_term(qb, kv, sv);
        t2 += quad_term(qc, kv, sv);
        t3 += quad_term(qd, kv, sv);

        if (i + 1 < 32) kv = nkv;
    }

    // unnormalized weights (S0 cancels in softmax); masked lanes exactly 0
    float wgt[4];
    wgt[0] = m ? __expf(-2.f * t0) : 0.f;
    wgt[1] = m ? __expf(-2.f * t1) : 0.f;
    wgt[2] = m ? __expf(-2.f * t2) : 0.f;
    wgt[3] = m ? __expf(-2.f * t3) : 0.f;

    __shared__ float reds[4][16];
    const int lane = tid & 63, wv = tid >> 6;   // 16 waves

    float ls[4] = {wgt[0], wgt[1], wgt[2], wgt[3]};
    #pragma unroll
    for (int off = 32; off > 0; off >>= 1) {
        #pragma unroll
        for (int r = 0; r < 4; ++r)
            ls[r] += __shfl_down(ls[r], off, 64);
    }
    if (lane == 0) {
        #pragma unroll
        for (int r = 0; r < 4; ++r) reds[r][wv] = ls[r];
    }
    __syncthreads();
    #pragma unroll
    for (int r = 0; r < 4; ++r) {
        float g = 0.f;
        #pragma unroll
        for (int w = 0; w < 16; ++w) g += reds[r][w];
        attn_out[(size_t)(b * DEC + dq0 + r) * ENC + tid] =
            wgt[r] * __builtin_amdgcn_rcpf(g);
    }
}

// ---------------------------------------------------------------------------
// Kernel 3: ctx = attn @ value. 512 blocks x 512 threads: 8 dec rows x 128
// h-cols per block. Attention rows staged in LDS via flat float4 copies
// (the 8 rows are contiguous in memory); weights fetched as same-address
// ds_read_b128 broadcasts (LDS pipe, co-issues with fma stream).
// Value loads software-pipelined depth-1. 8-way cross-wave reduce via LDS.
// ---------------------------------------------------------------------------
__global__ __launch_bounds__(512) void ctx_kernel(
    const float* __restrict__ attn, const float* __restrict__ value,
    float* __restrict__ ctx)
{
    __shared__ float attnS[8][ENC];     // 32 KB
    __shared__ float part[8][8][128];   // 32 KB

    const int bi   = blockIdx.x;                 // 0..511, XCD-swizzled
    const int b    = (bi >> 1) & 3;              // b pinned to an XCD pair
    const int idx  = ((bi >> 3) << 1) | (bi & 1);
    const int row0 = (idx >> 2) * 8;
    const int h0   = (idx & 3) * 128;
    const int tid  = threadIdx.x;
    const int lane = tid & 63;
    const int wv   = __builtin_amdgcn_readfirstlane(tid >> 6);  // 0..7

    // stage 8 attention rows: 8192 contiguous floats, 4x float4 per thread
    const float* ab = attn + (size_t)(b * DEC + row0) * ENC;
    #pragma unroll
    for (int k = 0; k < 4; ++k) {
        const float4 v = *(const float4*)(ab + (size_t)k * 2048 + tid * 4);
        *(float4*)&attnS[0][k * 2048 + tid * 4] = v;
    }
    __syncthreads();

    float acc[8][2];
    #pragma unroll
    for (int r = 0; r < 8; ++r) { acc[r][0] = 0.f; acc[r][1] = 0.f; }

    const float* vb = value + (size_t)b * ENC * HID + h0 + lane * 2;
    const int e0 = wv * 128;

    // preload group 0's value columns
    float2 va[4];
    #pragma unroll
    for (int j = 0; j < 4; ++j)
        va[j] = *(const float2*)(vb + (size_t)(e0 + j) * HID);

    for (int g = 0; g < 32; ++g) {                // 4-e groups
        const int gp = (g + 1 < 32) ? g + 1 : g;  // clamped prefetch
        float2 vn[4];
        #pragma unroll
        for (int j = 0; j < 4; ++j)
            vn[j] = *(const float2*)(vb + (size_t)(e0 + gp * 4 + j) * HID);

        const int eg = e0 + g * 4;
        float4 w4[8];
        #pragma unroll
        for (int r = 0; r < 8; ++r)
            w4[r] = *(const float4*)&attnS[r][eg];   // same-addr broadcast b128

        #pragma unroll
        for (int j = 0; j < 4; ++j) {
            const float2 v2 = va[j];
            #pragma unroll
            for (int r = 0; r < 8; ++r) {
                const float w = ((const float*)&w4[r])[j];
                acc[r][0] += w * v2.x;
                acc[r][1] += w * v2.y;
            }
        }
        #pragma unroll
        for (int j = 0; j < 4; ++j) va[j] = vn[j];
    }

    #pragma unroll
    for (int r = 0; r < 8; ++r)
        *(float2*)&part[wv][r][lane * 2] = make_float2(acc[r][0], acc[r][1]);
    __syncthreads();

    // 8-way cross-wave reduce: 1024 outputs, 2 per thread, stride-1 in h
    #pragma unroll
    for (int k = 0; k < 2; ++k) {
        const int idx2 = tid + k * 512;
        const int r = idx2 >> 7, hh = idx2 & 127;
        float s = 0.f;
        #pragma unroll
        for (int w = 0; w < 8; ++w) s += part[w][r][hh];
        ctx[(size_t)(b * DEC + row0 + r) * HID + h0 + hh] = s;
    }
}

extern "C" void kernel_launch(void* const* d_in, const int* in_sizes, int n_in,
                              void* d_out, int out_size, void* d_ws, size_t ws_size,
                              hipStream_t stream) {
    const float* query = (const float*)d_in[0];
    const float* value = (const float*)d_in[1];
    const int*   mask  = (const int*)  d_in[2];
    const float* W1    = (const float*)d_in[3];
    const float* W2    = (const float*)d_in[4];
    const float* scale = (const float*)d_in[5];

    float* qbuf  = (float*)d_ws;                       // B*DEC*UNITS   = 131072 floats
    float* kbufT = qbuf + (size_t)B * DEC * UNITS;     // B*32*ENC*4    = 524288 floats

    float* ctx_out  = (float*)d_out;                   // B*DEC*HID
    float* attn_out = ctx_out + (size_t)B * DEC * HID; // B*DEC*ENC

    proj_kernel <<<640,  256, 0, stream>>>(query, value, W1, W2, qbuf, kbufT);
    score_kernel<<<256, 1024, 0, stream>>>(qbuf, kbufT, mask, scale, attn_out);
    ctx_kernel  <<<512,  512, 0, stream>>>(attn_out, value, ctx_out);
}